// Round 1
// baseline (1076.030 us; speedup 1.0000x reference)
//
#include <hip/hip_runtime.h>
#include <math.h>

// Max-plus DP: out[b,t,k] = x[b,t,k] + max(out[b,t-1,k], out[b,t-1,k-1])
// B=32 batches x G=8 column groups = 256 blocks (1 wave each).
// Column groups pipeline with a 1-tile skew; boundary column is read from
// d_out, ordering via device-scope flags in d_ws.

#define BB 32
#define TT 2048
#define KK 1024
#define GG 8
#define WW (KK / GG)         // 128 columns per group, 2 per lane (float2)
#define RR 32                // rows per tile
#define NTILES (TT / RR)     // 64

__device__ __forceinline__ void tile_body(
    int r_, int g, int lane, int k0, int kc,
    const float* __restrict__ xp, float* __restrict__ op,
    int* upflag, int* myflag,
    float& pv0, float& pv1,
    float2 (&cur)[RR], float2 (&nxt)[RR])
{
    // 1) Issue next tile's x prefetch first, so it flies while we spin-wait.
    const int rn = r_ + 1;
    if (rn < NTILES) {
#pragma unroll
        for (int j = 0; j < RR; ++j) {
            nxt[j] = *(const float2*)(xp + (size_t)(rn * RR + j) * KK + kc);
        }
    }

    // 2) Wait for left-neighbor column group to finish its tile r_.
    if (g > 0) {
        while (__hip_atomic_load(upflag, __ATOMIC_RELAXED,
                                 __HIP_MEMORY_SCOPE_AGENT) < r_ + 1) {
            __builtin_amdgcn_s_sleep(2);
        }
        __builtin_amdgcn_fence(__ATOMIC_ACQUIRE, "agent");
    }

    // 3) Boundary column: lane j holds out[row = r_*RR-1+j, k0-1].
    //    row = -1 (t==0) uses 0.0f so that x + max(0,0) = x.
    float bval;
    if (g > 0) {
        int j = lane < RR ? lane : (RR - 1);  // stay within producer's guarantee
        int row = r_ * RR - 1 + j;
        bval = 0.0f;
        if (row >= 0) bval = op[(size_t)row * KK + (k0 - 1)];
    } else {
        bval = (r_ == 0 && lane == 0) ? 0.0f : -INFINITY;
    }

    // 4) Compute RR rows. No intra-row dependency: both operands are prev row.
#pragma unroll
    for (int j = 0; j < RR; ++j) {
        const int t = r_ * RR + j;
        float2 xv = cur[j];
        float left = __shfl_up(pv1, 1);      // prev row, col kc-1 (from lane-1)
        float bv = __shfl(bval, j);          // boundary for this row
        if (lane == 0) left = bv;
        float n0 = xv.x + fmaxf(pv0, left);
        float n1 = xv.y + fmaxf(pv1, pv0);
        pv0 = n0; pv1 = n1;
        float2 o; o.x = n0; o.y = n1;
        *(float2*)(op + (size_t)t * KK + kc) = o;
    }

    // 5) Publish tile completion (release drains our stores first).
    if (g < GG - 1 && lane == 0) {
        __hip_atomic_store(myflag, r_ + 1, __ATOMIC_RELEASE,
                           __HIP_MEMORY_SCOPE_AGENT);
    }
}

__global__ __launch_bounds__(64, 1)
void harddtw_pipe(const float* __restrict__ x, float* __restrict__ out,
                  int* __restrict__ flags)
{
    const int bid  = blockIdx.x;
    // bid = g*32 + b  =>  bid % 8 == b % 8: a batch's whole 8-group chain
    // shares one XCD (round-robin block->XCD), keeping flag/boundary traffic
    // in one L2.
    const int g    = bid >> 5;   // 0..7
    const int b    = bid & 31;   // 0..31
    const int lane = threadIdx.x;

    const int k0 = g * WW;
    const int kc = k0 + lane * 2;
    const size_t base = (size_t)b * TT * KK;
    const float* xp = x + base;
    float* op = out + base;

    int* myflag = flags + bid;
    int* upflag = flags + (g > 0 ? bid - 32 : bid);

    float pv0 = 0.0f, pv1 = 0.0f;   // prev-row values; 0-init makes row 0 = x
    float2 xa[RR], xb[RR];

    // Preload tile 0.
#pragma unroll
    for (int j = 0; j < RR; ++j)
        xa[j] = *(const float2*)(xp + (size_t)j * KK + kc);

    for (int r2 = 0; r2 < NTILES; r2 += 2) {
        tile_body(r2,     g, lane, k0, kc, xp, op, upflag, myflag, pv0, pv1, xa, xb);
        tile_body(r2 + 1, g, lane, k0, kc, xp, op, upflag, myflag, pv0, pv1, xb, xa);
    }
}

extern "C" void kernel_launch(void* const* d_in, const int* in_sizes, int n_in,
                              void* d_out, int out_size, void* d_ws, size_t ws_size,
                              hipStream_t stream) {
    (void)in_sizes; (void)n_in; (void)out_size; (void)ws_size;
    const float* x = (const float*)d_in[0];
    float* out = (float*)d_out;
    int* flags = (int*)d_ws;

    // Flags must be zero every call (ws is re-poisoned to 0xAA by the harness).
    hipMemsetAsync(flags, 0, BB * GG * sizeof(int), stream);

    harddtw_pipe<<<dim3(BB * GG), dim3(64), 0, stream>>>(x, out, flags);
}

// Round 2
// 854.592 us; speedup vs baseline: 1.2591x; 1.2591x over previous
//
#include <hip/hip_runtime.h>
#include <math.h>

// Max-plus DP: out[b,t,k] = x[b,t,k] + max(out[b,t-1,k], out[b,t-1,k-1])
// 32 batches x 8 column groups = 256 blocks, 1 wave each, 2 cols/lane.
// Column groups pipeline with tile skew. NO fences anywhere: cross-block
// traffic (flags + boundary column) uses relaxed agent-scope atomics, which
// go to the IF$ coherence point without L2 writeback/invalidate storms.

#define BB 32
#define TT 2048
#define KK 1024
#define GG 8
#define WW (KK / GG)      // 128 cols per group
#define RR 32             // rows per tile (flag granularity, also prefetch depth)
#define NT (TT / RR)      // 64 tiles

__global__ __launch_bounds__(64, 1)
void harddtw_pipe(const float* __restrict__ x, float* __restrict__ out,
                  int* __restrict__ flags)
{
    const int bid  = blockIdx.x;
    const int g    = bid >> 5;   // column group 0..7
    const int b    = bid & 31;   // batch
    const int lane = threadIdx.x;

    const int k0 = g * WW;
    const int kc = k0 + (lane << 1);
    const size_t base = (size_t)b * TT * KK;

    const float* xl = x + base + kc;           // this lane's x column pair
    float*       ol = out + base + kc;         // out cursor (row 0)
    const float* bb = out + base + (k0 - 1);   // boundary column (g>0 only)

    int* myflag = flags + bid;
    int* upflag = flags + bid - 32;            // same batch, group g-1

    // --- register prefetch ring: rows t..t+31 in flight ---
    float2 buf[RR];
#pragma unroll
    for (int j = 0; j < RR; ++j)
        buf[j] = *(const float2*)(xl + (size_t)j * KK);
    const float* xpre = xl + (size_t)RR * KK;  // next row to prefetch

    float pv0 = 0.0f, pv1 = 0.0f;              // prev-row values (0 => row0 = x)
    float bcur = -INFINITY, bnxt = -INFINITY;  // boundary vals, lane j = row j of tile

    if (g > 0) {
        // tile 0 boundary: rows -1..30 of column k0-1
        while (__hip_atomic_load(upflag, __ATOMIC_RELAXED,
                                 __HIP_MEMORY_SCOPE_AGENT) < 1)
            __builtin_amdgcn_s_sleep(1);
        __asm__ volatile("" ::: "memory");
        if (lane == 0) {
            bcur = 0.0f;                       // row -1: x + max(0,0) = x
        } else if (lane < RR) {
            bcur = __hip_atomic_load(bb + (size_t)(lane - 1) * KK,
                                     __ATOMIC_RELAXED, __HIP_MEMORY_SCOPE_AGENT);
        }
    }

#pragma unroll 1
    for (int r = 0; r < NT; ++r) {
        // Lag-2: require producer 2 tiles ahead, then issue next tile's
        // boundary loads now so their ~900cy latency hides behind this tile.
        if (g > 0 && r < NT - 1) {
            while (__hip_atomic_load(upflag, __ATOMIC_RELAXED,
                                     __HIP_MEMORY_SCOPE_AGENT) < r + 2)
                __builtin_amdgcn_s_sleep(1);
            __asm__ volatile("" ::: "memory");
            if (lane < RR)
                bnxt = __hip_atomic_load(
                    bb + (size_t)((r + 1) * RR + lane - 1) * KK,
                    __ATOMIC_RELAXED, __HIP_MEMORY_SCOPE_AGENT);
        }

        const bool pref = (r < NT - 1);
        const bool pub  = (g < GG - 1);

#pragma unroll
        for (int j = 0; j < RR; ++j) {
            float2 xv = buf[j];
            float left = __shfl_up(pv1, 1);    // prev row, col kc-1
            float bv = __shfl(bcur, j);        // boundary for this row
            if (lane == 0) left = bv;
            float n0 = xv.x + fmaxf(pv0, left);
            float n1 = xv.y + fmaxf(pv1, pv0);
            pv0 = n0; pv1 = n1;
            float2 o; o.x = n0; o.y = n1;
            if (pub && lane == 63) {
                // boundary pair must be IF$-visible: relaxed agent atomic 8B
                union { float2 f; unsigned long long u; } cv; cv.f = o;
                __hip_atomic_store((unsigned long long*)ol, cv.u,
                                   __ATOMIC_RELAXED, __HIP_MEMORY_SCOPE_AGENT);
            } else {
                *(float2*)ol = o;
            }
            ol += KK;
            if (pref) {                        // prefetch row t+RR into slot j
                buf[j] = *(const float2*)xpre;
                xpre += KK;
            }
            // Pin the software pipeline: nothing crosses row boundaries.
            __builtin_amdgcn_sched_barrier(0);
        }

        bcur = bnxt;

        if (pub) {
            // Drain our stores to the coherence point (wait only — no wbl2),
            // then publish. Consumer reads boundary only via agent atomics.
            __asm__ volatile("s_waitcnt vmcnt(0)" ::: "memory");
            if (lane == 0)
                __hip_atomic_store(myflag, r + 1, __ATOMIC_RELAXED,
                                   __HIP_MEMORY_SCOPE_AGENT);
        }
    }
}

extern "C" void kernel_launch(void* const* d_in, const int* in_sizes, int n_in,
                              void* d_out, int out_size, void* d_ws, size_t ws_size,
                              hipStream_t stream) {
    (void)in_sizes; (void)n_in; (void)out_size; (void)ws_size;
    const float* x = (const float*)d_in[0];
    float* out = (float*)d_out;
    int* flags = (int*)d_ws;

    // ws is re-poisoned to 0xAA before every timed launch; flags must be 0.
    hipMemsetAsync(flags, 0, BB * GG * sizeof(int), stream);

    harddtw_pipe<<<dim3(BB * GG), dim3(64), 0, stream>>>(x, out, flags);
}